// Round 1
// 1406.590 us; speedup vs baseline: 1.0127x; 1.0127x over previous
//
#include <hip/hip_runtime.h>
#include <math.h>

#define H 2048
#define IDIM 1408
#define TWO_I 2816
#define NE 8
#define NTOK 8192
#define BK 32

typedef float f32x4 __attribute__((ext_vector_type(4)));
typedef short bf16x8 __attribute__((ext_vector_type(8)));

// ---------------- workspace layout (bytes) ----------------
#define CNT_OFF   0
#define OFFS_OFF  64
#define BIDX_OFF  1024
#define BW_OFF    (BIDX_OFF + NE*NTOK*4)
#define GATE_OFF  (BW_OFF + NE*NTOK*4)
#define XS_OFF    ((size_t)1 << 20)
#define XS_ROWS   (NTOK + 2*NTOK)                     // 8192 unscaled + 16384 gathered*scaled
#define WGU_OFF   (XS_OFF  + (size_t)XS_ROWS*H*2)     // bf16 [E][2I][H]
#define WDN_OFF   (WGU_OFF + (size_t)NE*TWO_I*H*2)    // bf16 [E][H][I]
#define WSGU_OFF  (WDN_OFF + (size_t)NE*H*IDIM*2)     // bf16 [2I][H]
#define WSDN_OFF  (WSGU_OFF + (size_t)TWO_I*H*2)      // bf16 [H][I]
#define ACT_OFF   (WSDN_OFF + (size_t)H*IDIM*2)       // bf16 [16384][I]

// async global->LDS, 16B per lane; LDS dest is wave-uniform base + lane*16
#define GLOAD16(g, l) \
    __builtin_amdgcn_global_load_lds((const __attribute__((address_space(1))) void*)(g), \
                                     (__attribute__((address_space(3))) void*)(l), 16, 0, 0)

__device__ inline ushort f2bf(float f) {
    union { float f; uint u; } v; v.f = f;
    uint u = v.u;
    uint r = u + 0x7fffu + ((u >> 16) & 1u);   // RNE
    return (ushort)(r >> 16);
}

// ---------------- small utility kernels ----------------
__global__ void zero_meta_kernel(int* p) {
    if (threadIdx.x < 16) p[threadIdx.x] = 0;
}

__global__ void prefix_kernel(const int* __restrict__ cnt, int* __restrict__ offs) {
    if (threadIdx.x == 0) {
        int s = 0;
        for (int e = 0; e < NE; e++) { offs[e] = s; s += cnt[e]; }
    }
}

// ---------------- router ----------------
__global__ __launch_bounds__(64)
void router_kernel(const float* __restrict__ x,
                   const float* __restrict__ w_router,
                   const float* __restrict__ w_sgate,
                   int* __restrict__ cnt,
                   int* __restrict__ bidx,
                   float* __restrict__ bw,
                   float* __restrict__ gate) {
    const int t = blockIdx.x;
    const int lane = threadIdx.x;
    const float* xr = x + (size_t)t * H;

    float acc[NE];
#pragma unroll
    for (int e = 0; e < NE; e++) acc[e] = 0.f;
    float accg = 0.f;

    for (int h = lane; h < H; h += 64) {
        float xv = xr[h];
        const float* wr = w_router + (size_t)h * NE;
#pragma unroll
        for (int e = 0; e < NE; e++) acc[e] += xv * wr[e];
        accg += xv * w_sgate[h];
    }
#pragma unroll
    for (int off = 32; off > 0; off >>= 1) {
#pragma unroll
        for (int e = 0; e < NE; e++) acc[e] += __shfl_down(acc[e], off, 64);
        accg += __shfl_down(accg, off, 64);
    }
    if (lane == 0) {
        int i0 = 0; float v0 = acc[0];
        for (int e = 1; e < NE; e++) if (acc[e] > v0) { v0 = acc[e]; i0 = e; }
        int i1 = -1; float v1 = -3.4e38f;
        for (int e = 0; e < NE; e++) if (e != i0 && acc[e] > v1) { v1 = acc[e]; i1 = e; }
        float e1 = expf(v1 - v0);
        float inv = 1.f / (1.f + e1);
        int pos0 = atomicAdd(&cnt[i0], 1);
        bidx[i0 * NTOK + pos0] = t; bw[i0 * NTOK + pos0] = inv;
        int pos1 = atomicAdd(&cnt[i1], 1);
        bidx[i1 * NTOK + pos1] = t; bw[i1 * NTOK + pos1] = e1 * inv;
        gate[t] = 1.f / (1.f + expf(-accg));
    }
}

// ---------------- transpose + fp32->bf16 convert:  dst[c][r] = bf16(src[r][c]) ----------------
__global__ __launch_bounds__(256)
void transpose_cvt(const float* __restrict__ src, ushort* __restrict__ dst, int R, int C) {
    const size_t bs = (size_t)R * C;
    src += (size_t)blockIdx.z * bs;
    dst += (size_t)blockIdx.z * bs;
    const int c0 = blockIdx.x * 64, r0 = blockIdx.y * 64;
    __shared__ float t[64][65];
    const int tid = threadIdx.x;
#pragma unroll
    for (int p = 0; p < 4; p++) {
        int id = tid + p * 256;
        int r = id >> 4, c4 = (id & 15) * 4;
        float4 v = *(const float4*)(src + (size_t)(r0 + r) * C + c0 + c4);
        t[r][c4 + 0] = v.x; t[r][c4 + 1] = v.y; t[r][c4 + 2] = v.z; t[r][c4 + 3] = v.w;
    }
    __syncthreads();
#pragma unroll
    for (int p = 0; p < 4; p++) {
        int id = tid + p * 256;
        int c = id >> 4, r4 = (id & 15) * 4;
        union { ushort us[4]; uint2 v; } o;
#pragma unroll
        for (int q = 0; q < 4; q++) o.us[q] = f2bf(t[r4 + q][c]);
        *(uint2*)(dst + (size_t)(c0 + c) * R + r0 + r4) = o.v;
    }
}

// ---------------- x prep: bf16 convert; gathered + routing-weight scaled copies ----------------
__global__ __launch_bounds__(256)
void xprep_kernel(const float* __restrict__ x, const int* __restrict__ cnt,
                  const int* __restrict__ offs, const int* __restrict__ bidx,
                  const float* __restrict__ bw, ushort* __restrict__ xs) {
    const int y = blockIdx.y;
    const int r = blockIdx.x;
    int srow, drow; float wt;
    if (y == 0) { srow = r; drow = r; wt = 1.f; }
    else {
        int e = y - 1;
        if (r >= cnt[e]) return;
        srow = bidx[e * NTOK + r]; wt = bw[e * NTOK + r];
        drow = NTOK + offs[e] + r;
    }
    const int tid = threadIdx.x;
    const float* sp = x + (size_t)srow * H + tid * 8;
    float4 v0 = *(const float4*)sp;
    float4 v1 = *(const float4*)(sp + 4);
    union { ushort us[8]; uint4 v; } o;
    o.us[0] = f2bf(v0.x * wt); o.us[1] = f2bf(v0.y * wt);
    o.us[2] = f2bf(v0.z * wt); o.us[3] = f2bf(v0.w * wt);
    o.us[4] = f2bf(v1.x * wt); o.us[5] = f2bf(v1.y * wt);
    o.us[6] = f2bf(v1.z * wt); o.us[7] = f2bf(v1.w * wt);
    *(uint4*)(xs + (size_t)drow * H + tid * 8) = o.v;
}

// ---------------- gate_up MFMA GEMM with fused SwiGLU (global_load_lds staging) ----------------
// C tile 128(m) x 64(n of I); dual acc for gate (rows n of W^T) and up (rows I+n).
// act[obase+row][n] = bf16(silu(g)*u)
template <bool GATHER>
__global__ __launch_bounds__(256)
void gateup_mfma(const ushort* __restrict__ xs,
                 const ushort* __restrict__ wt,   // bf16 [E?][2I][H]
                 const int* __restrict__ cnt,
                 const int* __restrict__ offs,
                 ushort* __restrict__ act) {
    const int e = GATHER ? blockIdx.z : 0;
    const int rows = GATHER ? cnt[e] : NTOK;
    const int m0 = blockIdx.y * 128;
    if (GATHER && m0 >= rows) return;
    const int n0 = blockIdx.x * 64;
    const ushort* W = wt + (GATHER ? (size_t)e * TWO_I * H : 0);
    const int abase = GATHER ? (NTOK + offs[e]) : 0;
    const int obase = GATHER ? offs[e] : 0;

    // linear LDS (required by global_load_lds: wave-uniform base + lane*16)
    __shared__ __align__(16) ushort As[128 * BK];   // 8 KiB
    __shared__ __align__(16) ushort Bg[64 * BK];    // 4 KiB
    __shared__ __align__(16) ushort Bu[64 * BK];    // 4 KiB

    const int tid = threadIdx.x;
    const int wave = tid >> 6, lane = tid & 63;
    const int wm = (wave >> 1) * 64, wn = (wave & 1) * 32;
    const int quad = lane >> 4, l16 = lane & 15;

    // staging map: each wave DMAs one contiguous 1 KiB LDS chunk (16 rows x 64B)
    const int lr = wave * 16 + (lane >> 2);   // row 0..63 within a 64-row slab
    const int lc = (lane & 3) * 8;            // ushort col offset 0,8,16,24
    int ga0 = m0 + lr, ga1 = m0 + 64 + lr;
    if (GATHER) {                             // clamp OOB rows to a valid row;
        if (ga0 >= rows) ga0 = m0;            // garbage acc rows are masked at store
        if (ga1 >= rows) ga1 = m0;
    }
    const ushort* a0p = xs + (size_t)(abase + ga0) * H + lc;
    const ushort* a1p = xs + (size_t)(abase + ga1) * H + lc;
    const ushort* bgp = W + (size_t)(n0 + lr) * H + lc;
    const ushort* bup = W + (size_t)(IDIM + n0 + lr) * H + lc;
    char* asl0 = (char*)As + wave * 1024;
    char* asl1 = (char*)As + 4096 + wave * 1024;
    char* bgl  = (char*)Bg + wave * 1024;
    char* bul  = (char*)Bu + wave * 1024;

    f32x4 accg[4][2], accu[4][2];
#pragma unroll
    for (int i = 0; i < 4; i++)
#pragma unroll
        for (int j = 0; j < 2; j++) { accg[i][j] = (f32x4)0.f; accu[i][j] = (f32x4)0.f; }

    for (int k0 = 0; k0 < H; k0 += BK) {
        GLOAD16(a0p + k0, asl0);
        GLOAD16(a1p + k0, asl1);
        GLOAD16(bgp + k0, bgl);
        GLOAD16(bup + k0, bul);
        __syncthreads();                 // drains vmcnt: tiles resident
        bf16x8 af[4], bgf[2], buf[2];
#pragma unroll
        for (int i = 0; i < 4; i++)
            af[i] = *(const bf16x8*)&As[(wm + i * 16 + l16) * BK + quad * 8];
#pragma unroll
        for (int j = 0; j < 2; j++) {
            bgf[j] = *(const bf16x8*)&Bg[(wn + j * 16 + l16) * BK + quad * 8];
            buf[j] = *(const bf16x8*)&Bu[(wn + j * 16 + l16) * BK + quad * 8];
        }
#pragma unroll
        for (int i = 0; i < 4; i++)
#pragma unroll
            for (int j = 0; j < 2; j++) {
                accg[i][j] = __builtin_amdgcn_mfma_f32_16x16x32_bf16(af[i], bgf[j], accg[i][j], 0, 0, 0);
                accu[i][j] = __builtin_amdgcn_mfma_f32_16x16x32_bf16(af[i], buf[j], accu[i][j], 0, 0, 0);
            }
        __syncthreads();                 // all reads done before next DMA overwrites
    }

#pragma unroll
    for (int i = 0; i < 4; i++) {
#pragma unroll
        for (int r = 0; r < 4; r++) {
            int row = m0 + wm + i * 16 + quad * 4 + r;
            if (row >= rows) continue;
            ushort* orow = act + (size_t)(obase + row) * IDIM + n0 + wn + l16;
#pragma unroll
            for (int j = 0; j < 2; j++) {
                float g = accg[i][j][r], u = accu[i][j][r];
                float v = g / (1.f + expf(-g)) * u;
                orow[j * 16] = f2bf(v);
            }
        }
    }
}

// ---------------- down MFMA GEMM (global_load_lds staging) ----------------
// SCATTER=false: out[row][n] = gate[row] * dot ; SCATTER=true: atomicAdd(out[token][n], dot)
template <bool SCATTER>
__global__ __launch_bounds__(256)
void down_mfma(const ushort* __restrict__ act,
               const ushort* __restrict__ wt,    // bf16 [E?][H][I]
               const int* __restrict__ cnt,
               const int* __restrict__ offs,
               const int* __restrict__ bidx,
               const float* __restrict__ gate,
               float* __restrict__ out) {
    const int e = SCATTER ? blockIdx.z : 0;
    const int rows = SCATTER ? cnt[e] : NTOK;
    const int m0 = blockIdx.y * 128;
    if (SCATTER && m0 >= rows) return;
    const int n0 = blockIdx.x * 128;
    const ushort* W = wt + (SCATTER ? (size_t)e * H * IDIM : 0);
    const ushort* A = act + (size_t)(SCATTER ? offs[e] : 0) * IDIM;

    __shared__ __align__(16) ushort As[128 * BK];   // 8 KiB
    __shared__ __align__(16) ushort Bs[128 * BK];   // 8 KiB

    const int tid = threadIdx.x;
    const int wave = tid >> 6, lane = tid & 63;
    const int wm = (wave >> 1) * 64, wn = (wave & 1) * 64;
    const int quad = lane >> 4, l16 = lane & 15;

    const int lr = wave * 16 + (lane >> 2);
    const int lc = (lane & 3) * 8;
    int ga0 = m0 + lr, ga1 = m0 + 64 + lr;
    if (SCATTER) {
        if (ga0 >= rows) ga0 = m0;
        if (ga1 >= rows) ga1 = m0;
    }
    const ushort* a0p = A + (size_t)ga0 * IDIM + lc;
    const ushort* a1p = A + (size_t)ga1 * IDIM + lc;
    const ushort* b0p = W + (size_t)(n0 + lr) * IDIM + lc;
    const ushort* b1p = W + (size_t)(n0 + 64 + lr) * IDIM + lc;
    char* asl0 = (char*)As + wave * 1024;
    char* asl1 = (char*)As + 4096 + wave * 1024;
    char* bsl0 = (char*)Bs + wave * 1024;
    char* bsl1 = (char*)Bs + 4096 + wave * 1024;

    f32x4 acc[4][4];
#pragma unroll
    for (int i = 0; i < 4; i++)
#pragma unroll
        for (int j = 0; j < 4; j++) acc[i][j] = (f32x4)0.f;

    for (int k0 = 0; k0 < IDIM; k0 += BK) {
        GLOAD16(a0p + k0, asl0);
        GLOAD16(a1p + k0, asl1);
        GLOAD16(b0p + k0, bsl0);
        GLOAD16(b1p + k0, bsl1);
        __syncthreads();
        bf16x8 af[4], bf[4];
#pragma unroll
        for (int i = 0; i < 4; i++)
            af[i] = *(const bf16x8*)&As[(wm + i * 16 + l16) * BK + quad * 8];
#pragma unroll
        for (int j = 0; j < 4; j++)
            bf[j] = *(const bf16x8*)&Bs[(wn + j * 16 + l16) * BK + quad * 8];
#pragma unroll
        for (int i = 0; i < 4; i++)
#pragma unroll
            for (int j = 0; j < 4; j++)
                acc[i][j] = __builtin_amdgcn_mfma_f32_16x16x32_bf16(af[i], bf[j], acc[i][j], 0, 0, 0);
        __syncthreads();
    }

#pragma unroll
    for (int i = 0; i < 4; i++) {
#pragma unroll
        for (int r = 0; r < 4; r++) {
            int row = m0 + wm + i * 16 + quad * 4 + r;
            if (row >= rows) continue;
            if (SCATTER) {
                int token = bidx[e * NTOK + row];
                float* orow = out + (size_t)token * H + n0 + wn + l16;
#pragma unroll
                for (int j = 0; j < 4; j++) atomicAdd(&orow[j * 16], acc[i][j][r]);
            } else {
                float gv = gate[row];
                float* orow = out + (size_t)row * H + n0 + wn + l16;
#pragma unroll
                for (int j = 0; j < 4; j++) orow[j * 16] = gv * acc[i][j][r];
            }
        }
    }
}

// ---------------- launch ----------------
extern "C" void kernel_launch(void* const* d_in, const int* in_sizes, int n_in,
                              void* d_out, int out_size, void* d_ws, size_t ws_size,
                              hipStream_t stream) {
    const float* x     = (const float*)d_in[0];
    const float* w_rt  = (const float*)d_in[1];
    const float* w_gu  = (const float*)d_in[2];
    const float* w_dn  = (const float*)d_in[3];
    const float* w_sgu = (const float*)d_in[4];
    const float* w_sdn = (const float*)d_in[5];
    const float* w_sg  = (const float*)d_in[6];
    float* out = (float*)d_out;

    char* ws = (char*)d_ws;
    int*    cnt   = (int*)(ws + CNT_OFF);
    int*    offs  = (int*)(ws + OFFS_OFF);
    int*    bidx  = (int*)(ws + BIDX_OFF);
    float*  bw    = (float*)(ws + BW_OFF);
    float*  gate  = (float*)(ws + GATE_OFF);
    ushort* xs    = (ushort*)(ws + XS_OFF);
    ushort* wgu_t = (ushort*)(ws + WGU_OFF);
    ushort* wdn_t = (ushort*)(ws + WDN_OFF);
    ushort* wsgu_t= (ushort*)(ws + WSGU_OFF);
    ushort* wsdn_t= (ushort*)(ws + WSDN_OFF);
    ushort* act   = (ushort*)(ws + ACT_OFF);

    zero_meta_kernel<<<1, 64, 0, stream>>>(cnt);
    router_kernel<<<NTOK, 64, 0, stream>>>(x, w_rt, w_sg, cnt, bidx, bw, gate);
    prefix_kernel<<<1, 64, 0, stream>>>(cnt, offs);

    // weight transpose+convert: [R][C] fp32 -> [C][R] bf16
    transpose_cvt<<<dim3(TWO_I / 64, H / 64, NE), 256, 0, stream>>>(w_gu, wgu_t, H, TWO_I);
    transpose_cvt<<<dim3(H / 64, IDIM / 64, NE), 256, 0, stream>>>(w_dn, wdn_t, IDIM, H);
    transpose_cvt<<<dim3(TWO_I / 64, H / 64, 1), 256, 0, stream>>>(w_sgu, wsgu_t, H, TWO_I);
    transpose_cvt<<<dim3(H / 64, IDIM / 64, 1), 256, 0, stream>>>(w_sdn, wsdn_t, IDIM, H);

    // x -> bf16 (unscaled + gathered*scaled bucket copies)
    xprep_kernel<<<dim3(NTOK, NE + 1), 256, 0, stream>>>(x, cnt, offs, bidx, bw, xs);

    // shared expert
    gateup_mfma<false><<<dim3(IDIM / 64, NTOK / 128), 256, 0, stream>>>(xs, wsgu_t, cnt, offs, act);
    down_mfma<false><<<dim3(H / 128, NTOK / 128), 256, 0, stream>>>(act, wsdn_t, cnt, offs, bidx, gate, out);

    // routed experts
    gateup_mfma<true><<<dim3(IDIM / 64, NTOK / 128, NE), 256, 0, stream>>>(xs, wgu_t, cnt, offs, act);
    down_mfma<true><<<dim3(H / 128, NTOK / 128, NE), 256, 0, stream>>>(act, wdn_t, cnt, offs, bidx, gate, out);
}

// Round 2
// 1382.730 us; speedup vs baseline: 1.0302x; 1.0173x over previous
//
#include <hip/hip_runtime.h>
#include <math.h>

#define H 2048
#define IDIM 1408
#define TWO_I 2816
#define NE 8
#define NTOK 8192
#define BK 32

typedef float f32x4 __attribute__((ext_vector_type(4)));
typedef short bf16x8 __attribute__((ext_vector_type(8)));

// ---------------- workspace layout (bytes) ----------------
#define CNT_OFF   0
#define OFFS_OFF  64
#define BIDX_OFF  1024
#define BW_OFF    (BIDX_OFF + NE*NTOK*4)
#define GATE_OFF  (BW_OFF + NE*NTOK*4)
#define XS_OFF    ((size_t)1 << 20)
#define XS_ROWS   (NTOK + 2*NTOK)                     // 8192 unscaled + 16384 gathered*scaled
#define WGU_OFF   (XS_OFF  + (size_t)XS_ROWS*H*2)     // bf16 [E][2I][H] (g/u 16-row interleave)
#define WDN_OFF   (WGU_OFF + (size_t)NE*TWO_I*H*2)    // bf16 [E][H][I]
#define WSGU_OFF  (WDN_OFF + (size_t)NE*H*IDIM*2)     // bf16 [2I][H] (interleaved)
#define WSDN_OFF  (WSGU_OFF + (size_t)TWO_I*H*2)      // bf16 [H][I]
#define ACT_OFF   (WSDN_OFF + (size_t)H*IDIM*2)       // bf16 [16384][I]

// async global->LDS, 16B per lane; LDS dest is wave-uniform base + lane*16
#define GLOAD16(g, l) \
    __builtin_amdgcn_global_load_lds((const __attribute__((address_space(1))) void*)(g), \
                                     (__attribute__((address_space(3))) void*)(l), 16, 0, 0)

__device__ inline void wave_barrier() {
    asm volatile("" ::: "memory");
    __builtin_amdgcn_s_barrier();
    asm volatile("" ::: "memory");
}

__device__ inline ushort f2bf(float f) {
    union { float f; uint u; } v; v.f = f;
    uint u = v.u;
    uint r = u + 0x7fffu + ((u >> 16) & 1u);   // RNE
    return (ushort)(r >> 16);
}

// ---------------- small utility kernels ----------------
__global__ void zero_meta_kernel(int* p) {
    if (threadIdx.x < 16) p[threadIdx.x] = 0;
}

__global__ void prefix_kernel(const int* __restrict__ cnt, int* __restrict__ offs) {
    if (threadIdx.x == 0) {
        int s = 0;
        for (int e = 0; e < NE; e++) { offs[e] = s; s += cnt[e]; }
    }
}

// ---------------- router ----------------
__global__ __launch_bounds__(64)
void router_kernel(const float* __restrict__ x,
                   const float* __restrict__ w_router,
                   const float* __restrict__ w_sgate,
                   int* __restrict__ cnt,
                   int* __restrict__ bidx,
                   float* __restrict__ bw,
                   float* __restrict__ gate) {
    const int t = blockIdx.x;
    const int lane = threadIdx.x;
    const float* xr = x + (size_t)t * H;

    float acc[NE];
#pragma unroll
    for (int e = 0; e < NE; e++) acc[e] = 0.f;
    float accg = 0.f;

    for (int h = lane; h < H; h += 64) {
        float xv = xr[h];
        const float* wr = w_router + (size_t)h * NE;
#pragma unroll
        for (int e = 0; e < NE; e++) acc[e] += xv * wr[e];
        accg += xv * w_sgate[h];
    }
#pragma unroll
    for (int off = 32; off > 0; off >>= 1) {
#pragma unroll
        for (int e = 0; e < NE; e++) acc[e] += __shfl_down(acc[e], off, 64);
        accg += __shfl_down(accg, off, 64);
    }
    if (lane == 0) {
        int i0 = 0; float v0 = acc[0];
        for (int e = 1; e < NE; e++) if (acc[e] > v0) { v0 = acc[e]; i0 = e; }
        int i1 = -1; float v1 = -3.4e38f;
        for (int e = 0; e < NE; e++) if (e != i0 && acc[e] > v1) { v1 = acc[e]; i1 = e; }
        float e1 = expf(v1 - v0);
        float inv = 1.f / (1.f + e1);
        int pos0 = atomicAdd(&cnt[i0], 1);
        bidx[i0 * NTOK + pos0] = t; bw[i0 * NTOK + pos0] = inv;
        int pos1 = atomicAdd(&cnt[i1], 1);
        bidx[i1 * NTOK + pos1] = t; bw[i1 * NTOK + pos1] = e1 * inv;
        gate[t] = 1.f / (1.f + expf(-accg));
    }
}

// ---------------- transpose + fp32->bf16 convert:  dst[perm(c)][r] = bf16(src[r][c]) ----------------
// perm=1 (gate_up weights): gate col i -> row 32*(i/16)+(i%16); up col i -> +16 (16-block interleave)
__global__ __launch_bounds__(256)
void transpose_cvt(const float* __restrict__ src, ushort* __restrict__ dst, int R, int C, int perm) {
    const size_t bs = (size_t)R * C;
    src += (size_t)blockIdx.z * bs;
    dst += (size_t)blockIdx.z * bs;
    const int c0 = blockIdx.x * 64, r0 = blockIdx.y * 64;
    __shared__ float t[64][65];
    const int tid = threadIdx.x;
#pragma unroll
    for (int p = 0; p < 4; p++) {
        int id = tid + p * 256;
        int r = id >> 4, c4 = (id & 15) * 4;
        float4 v = *(const float4*)(src + (size_t)(r0 + r) * C + c0 + c4);
        t[r][c4 + 0] = v.x; t[r][c4 + 1] = v.y; t[r][c4 + 2] = v.z; t[r][c4 + 3] = v.w;
    }
    __syncthreads();
#pragma unroll
    for (int p = 0; p < 4; p++) {
        int id = tid + p * 256;
        int c = id >> 4, r4 = (id & 15) * 4;
        union { ushort us[4]; uint2 v; } o;
#pragma unroll
        for (int q = 0; q < 4; q++) o.us[q] = f2bf(t[r4 + q][c]);
        int g = c0 + c;
        int drow = g;
        if (perm) {
            drow = (g < IDIM) ? (((g >> 4) << 5) | (g & 15))
                              : ((((g - IDIM) >> 4) << 5) | 16 | (g & 15));
        }
        *(uint2*)(dst + (size_t)drow * R + r0 + r4) = o.v;
    }
}

// ---------------- x prep: bf16 convert; gathered + routing-weight scaled copies ----------------
__global__ __launch_bounds__(256)
void xprep_kernel(const float* __restrict__ x, const int* __restrict__ cnt,
                  const int* __restrict__ offs, const int* __restrict__ bidx,
                  const float* __restrict__ bw, ushort* __restrict__ xs) {
    const int y = blockIdx.y;
    const int r = blockIdx.x;
    int srow, drow; float wt;
    if (y == 0) { srow = r; drow = r; wt = 1.f; }
    else {
        int e = y - 1;
        if (r >= cnt[e]) return;
        srow = bidx[e * NTOK + r]; wt = bw[e * NTOK + r];
        drow = NTOK + offs[e] + r;
    }
    const int tid = threadIdx.x;
    const float* sp = x + (size_t)srow * H + tid * 8;
    float4 v0 = *(const float4*)sp;
    float4 v1 = *(const float4*)(sp + 4);
    union { ushort us[8]; uint4 v; } o;
    o.us[0] = f2bf(v0.x * wt); o.us[1] = f2bf(v0.y * wt);
    o.us[2] = f2bf(v0.z * wt); o.us[3] = f2bf(v0.w * wt);
    o.us[4] = f2bf(v1.x * wt); o.us[5] = f2bf(v1.y * wt);
    o.us[6] = f2bf(v1.z * wt); o.us[7] = f2bf(v1.w * wt);
    *(uint4*)(xs + (size_t)drow * H + tid * 8) = o.v;
}

// =====================================================================
// 256x256 deep-pipelined MFMA GEMM template pieces (BK=32, 4-deep ring,
// counted vmcnt(8), one raw barrier per K-tile, st_16x32 LDS swizzle).
//
// LDS tile [256 rows][32 k] bf16 stored as 16x32 subtiles (1024B):
//   ushort_off(R,C) = (R>>4)*512 + (R&15)*32 + ((C>>3)*8 ^ ((R>>3)&1)*16) + (C&7)
// DMA writes linearly: wave w, round r -> subtile (r*8+w); per-lane GLOBAL
// source is inverse-swizzled:
//   row = r*128 + w*16 + (lane>>2), col = ((lane&3)*8) ^ ((lane>>5)*16)
// =====================================================================

// ---------------- gate_up: C tile 256(m) x 256(interleaved g/u n), fused SwiGLU ----------------
template <bool GATHER>
__global__ __launch_bounds__(512, 2)
void gateup_mfma(const ushort* __restrict__ xs,
                 const ushort* __restrict__ wt,   // bf16 [E?][2I][H], g/u interleaved rows
                 const int* __restrict__ cnt,
                 const int* __restrict__ offs,
                 ushort* __restrict__ act) {
    const int e = GATHER ? blockIdx.z : 0;
    const int rows = GATHER ? cnt[e] : NTOK;
    const int m0 = blockIdx.y * 256;
    if (GATHER && m0 >= rows) return;
    const int n0 = blockIdx.x * 256;
    const ushort* W = wt + (GATHER ? (size_t)e * TWO_I * H : 0);
    const int abase = GATHER ? (NTOK + offs[e]) : 0;
    const int obase = GATHER ? offs[e] : 0;

    __shared__ __align__(16) ushort sA[4 * 8192];   // 64 KiB: 4-deep A ring
    __shared__ __align__(16) ushort sB[4 * 8192];   // 64 KiB: 4-deep B ring

    const int tid = threadIdx.x;
    const int w = tid >> 6, lane = tid & 63;
    const int waveM = w >> 2, waveN = w & 3;
    const int quad = lane >> 4, l16 = lane & 15;

    // staging addressing (inverse-swizzled global source)
    const int sRow = (w << 4) + (lane >> 2);
    const int sCol = ((lane & 3) * 8) ^ ((lane >> 5) * 16);
    int ar0 = m0 + sRow, ar1 = m0 + 128 + sRow;
    if (GATHER) { int rm = rows - 1; ar0 = min(ar0, rm); ar1 = min(ar1, rm); }
    const ushort* aG0 = xs + (size_t)(abase + ar0) * H + sCol;
    const ushort* aG1 = xs + (size_t)(abase + ar1) * H + sCol;
    const ushort* bG0 = W + (size_t)(n0 + sRow) * H + sCol;
    const ushort* bG1 = W + (size_t)(n0 + 128 + sRow) * H + sCol;

    // swizzled ds_read offset (rb=0)
    const int rdo = l16 * 32 + ((quad * 8) ^ ((l16 >> 3) * 16));

    f32x4 acc[8][4];
#pragma unroll
    for (int i = 0; i < 8; i++)
#pragma unroll
        for (int j = 0; j < 4; j++) acc[i][j] = (f32x4)0.f;

    const int nkt = H / BK;   // 64

    // prologue: stage K-tiles 0,1,2 (12 loads/thread), drain tile0, barrier
#pragma unroll
    for (int pt = 0; pt < 3; ++pt) {
        const size_t ko = (size_t)pt * BK;
        GLOAD16(aG0 + ko, sA + pt * 8192 + w * 512);
        GLOAD16(aG1 + ko, sA + pt * 8192 + 4096 + w * 512);
        GLOAD16(bG0 + ko, sB + pt * 8192 + w * 512);
        GLOAD16(bG1 + ko, sB + pt * 8192 + 4096 + w * 512);
    }
    asm volatile("s_waitcnt vmcnt(8)" ::: "memory");
    wave_barrier();

    for (int t = 0; t < nkt; ++t) {
        const int bt = t & 3, btS = (t + 3) & 3;
        const int ktS = (t + 3 < nkt) ? (t + 3) : (nkt - 1);
        const size_t koS = (size_t)ktS * BK;
        const ushort* Ab = sA + bt * 8192;
        const ushort* Bb = sB + bt * 8192;

        bf16x8 fb[4];
#pragma unroll
        for (int j = 0; j < 4; ++j)
            fb[j] = *(const bf16x8*)(Bb + (waveN * 4 + j) * 512 + rdo);

#pragma unroll
        for (int mh = 0; mh < 2; ++mh) {
            bf16x8 fa[4];
#pragma unroll
            for (int i = 0; i < 4; ++i)
                fa[i] = *(const bf16x8*)(Ab + (waveM * 8 + mh * 4 + i) * 512 + rdo);
            __builtin_amdgcn_s_setprio(1);
#pragma unroll
            for (int i = 0; i < 4; ++i)
#pragma unroll
                for (int j = 0; j < 4; ++j)
                    acc[mh * 4 + i][j] = __builtin_amdgcn_mfma_f32_16x16x32_bf16(
                        fa[i], fb[j], acc[mh * 4 + i][j], 0, 0, 0);
            __builtin_amdgcn_s_setprio(0);
            if (mh == 0) {   // stage A half of K-tile t+3
                GLOAD16(aG0 + koS, sA + btS * 8192 + w * 512);
                GLOAD16(aG1 + koS, sA + btS * 8192 + 4096 + w * 512);
            } else {         // stage B half of K-tile t+3
                GLOAD16(bG0 + koS, sB + btS * 8192 + w * 512);
                GLOAD16(bG1 + koS, sB + btS * 8192 + 4096 + w * 512);
            }
        }
        asm volatile("s_waitcnt vmcnt(8)" ::: "memory");   // counted: never drain to 0
        wave_barrier();
    }
    asm volatile("s_waitcnt vmcnt(0)" ::: "memory");       // retire stale prefetches

    // epilogue: fuse SwiGLU over interleaved gate/up fragment pairs
    const int icolBase = (n0 + waveN * 64) >> 1;
#pragma unroll
    for (int i2 = 0; i2 < 8; ++i2) {
#pragma unroll
        for (int r = 0; r < 4; ++r) {
            int row = m0 + waveM * 128 + i2 * 16 + quad * 4 + r;
            if (row >= rows) continue;
            ushort* orow = act + (size_t)(obase + row) * IDIM + icolBase + l16;
#pragma unroll
            for (int p = 0; p < 2; ++p) {
                float g = acc[i2][2 * p][r], u = acc[i2][2 * p + 1][r];
                float v = g / (1.f + expf(-g)) * u;
                orow[p * 16] = f2bf(v);
            }
        }
    }
}

// ---------------- down: C tile 256(m) x 256(n of H) ----------------
template <bool SCATTER>
__global__ __launch_bounds__(512, 2)
void down_mfma(const ushort* __restrict__ act,
               const ushort* __restrict__ wt,    // bf16 [E?][H][I]
               const int* __restrict__ cnt,
               const int* __restrict__ offs,
               const int* __restrict__ bidx,
               const float* __restrict__ gate,
               float* __restrict__ out) {
    const int e = SCATTER ? blockIdx.z : 0;
    const int rows = SCATTER ? cnt[e] : NTOK;
    const int m0 = blockIdx.y * 256;
    if (SCATTER && m0 >= rows) return;
    const int n0 = blockIdx.x * 256;
    const ushort* W = wt + (SCATTER ? (size_t)e * H * IDIM : 0);
    const ushort* A = act + (size_t)(SCATTER ? offs[e] : 0) * IDIM;

    __shared__ __align__(16) ushort sA[4 * 8192];
    __shared__ __align__(16) ushort sB[4 * 8192];

    const int tid = threadIdx.x;
    const int w = tid >> 6, lane = tid & 63;
    const int waveM = w >> 2, waveN = w & 3;
    const int quad = lane >> 4, l16 = lane & 15;

    const int sRow = (w << 4) + (lane >> 2);
    const int sCol = ((lane & 3) * 8) ^ ((lane >> 5) * 16);
    int ar0 = m0 + sRow, ar1 = m0 + 128 + sRow;
    if (SCATTER) { int rm = rows - 1; ar0 = min(ar0, rm); ar1 = min(ar1, rm); }
    const ushort* aG0 = A + (size_t)ar0 * IDIM + sCol;
    const ushort* aG1 = A + (size_t)ar1 * IDIM + sCol;
    const ushort* bG0 = W + (size_t)(n0 + sRow) * IDIM + sCol;
    const ushort* bG1 = W + (size_t)(n0 + 128 + sRow) * IDIM + sCol;

    const int rdo = l16 * 32 + ((quad * 8) ^ ((l16 >> 3) * 16));

    f32x4 acc[8][4];
#pragma unroll
    for (int i = 0; i < 8; i++)
#pragma unroll
        for (int j = 0; j < 4; j++) acc[i][j] = (f32x4)0.f;

    const int nkt = IDIM / BK;   // 44

#pragma unroll
    for (int pt = 0; pt < 3; ++pt) {
        const size_t ko = (size_t)pt * BK;
        GLOAD16(aG0 + ko, sA + pt * 8192 + w * 512);
        GLOAD16(aG1 + ko, sA + pt * 8192 + 4096 + w * 512);
        GLOAD16(bG0 + ko, sB + pt * 8192 + w * 512);
        GLOAD16(bG1 + ko, sB + pt * 8192 + 4096 + w * 512);
    }
    asm volatile("s_waitcnt vmcnt(8)" ::: "memory");
    wave_barrier();

    for (int t = 0; t < nkt; ++t) {
        const int bt = t & 3, btS = (t + 3) & 3;
        const int ktS = (t + 3 < nkt) ? (t + 3) : (nkt - 1);
        const size_t koS = (size_t)ktS * BK;
        const ushort* Ab = sA + bt * 8192;
        const ushort* Bb = sB + bt * 8192;

        bf16x8 fb[4];
#pragma unroll
        for (int j = 0; j < 4; ++j)
            fb[j] = *(const bf16x8*)(Bb + (waveN * 4 + j) * 512 + rdo);

#pragma unroll
        for (int mh = 0; mh < 2; ++mh) {
            bf16x8 fa[4];
#pragma unroll
            for (int i = 0; i < 4; ++i)
                fa[i] = *(const bf16x8*)(Ab + (waveM * 8 + mh * 4 + i) * 512 + rdo);
            __builtin_amdgcn_s_setprio(1);
#pragma unroll
            for (int i = 0; i < 4; ++i)
#pragma unroll
                for (int j = 0; j < 4; ++j)
                    acc[mh * 4 + i][j] = __builtin_amdgcn_mfma_f32_16x16x32_bf16(
                        fa[i], fb[j], acc[mh * 4 + i][j], 0, 0, 0);
            __builtin_amdgcn_s_setprio(0);
            if (mh == 0) {
                GLOAD16(aG0 + koS, sA + btS * 8192 + w * 512);
                GLOAD16(aG1 + koS, sA + btS * 8192 + 4096 + w * 512);
            } else {
                GLOAD16(bG0 + koS, sB + btS * 8192 + w * 512);
                GLOAD16(bG1 + koS, sB + btS * 8192 + 4096 + w * 512);
            }
        }
        asm volatile("s_waitcnt vmcnt(8)" ::: "memory");
        wave_barrier();
    }
    asm volatile("s_waitcnt vmcnt(0)" ::: "memory");

#pragma unroll
    for (int i2 = 0; i2 < 8; ++i2) {
#pragma unroll
        for (int r = 0; r < 4; ++r) {
            int row = m0 + waveM * 128 + i2 * 16 + quad * 4 + r;
            if (row >= rows) continue;
            if (SCATTER) {
                int token = bidx[e * NTOK + row];
                float* orow = out + (size_t)token * H + n0 + waveN * 64 + l16;
#pragma unroll
                for (int j = 0; j < 4; ++j) atomicAdd(&orow[j * 16], acc[i2][j][r]);
            } else {
                float gv = gate[row];
                float* orow = out + (size_t)row * H + n0 + waveN * 64 + l16;
#pragma unroll
                for (int j = 0; j < 4; ++j) orow[j * 16] = gv * acc[i2][j][r];
            }
        }
    }
}

// ---------------- launch ----------------
extern "C" void kernel_launch(void* const* d_in, const int* in_sizes, int n_in,
                              void* d_out, int out_size, void* d_ws, size_t ws_size,
                              hipStream_t stream) {
    const float* x     = (const float*)d_in[0];
    const float* w_rt  = (const float*)d_in[1];
    const float* w_gu  = (const float*)d_in[2];
    const float* w_dn  = (const float*)d_in[3];
    const float* w_sgu = (const float*)d_in[4];
    const float* w_sdn = (const float*)d_in[5];
    const float* w_sg  = (const float*)d_in[6];
    float* out = (float*)d_out;

    char* ws = (char*)d_ws;
    int*    cnt   = (int*)(ws + CNT_OFF);
    int*    offs  = (int*)(ws + OFFS_OFF);
    int*    bidx  = (int*)(ws + BIDX_OFF);
    float*  bw    = (float*)(ws + BW_OFF);
    float*  gate  = (float*)(ws + GATE_OFF);
    ushort* xs    = (ushort*)(ws + XS_OFF);
    ushort* wgu_t = (ushort*)(ws + WGU_OFF);
    ushort* wdn_t = (ushort*)(ws + WDN_OFF);
    ushort* wsgu_t= (ushort*)(ws + WSGU_OFF);
    ushort* wsdn_t= (ushort*)(ws + WSDN_OFF);
    ushort* act   = (ushort*)(ws + ACT_OFF);

    zero_meta_kernel<<<1, 64, 0, stream>>>(cnt);
    router_kernel<<<NTOK, 64, 0, stream>>>(x, w_rt, w_sg, cnt, bidx, bw, gate);
    prefix_kernel<<<1, 64, 0, stream>>>(cnt, offs);

    // weight transpose+convert: [R][C] fp32 -> [C][R] bf16 (gate_up: 16-block g/u interleave)
    transpose_cvt<<<dim3(TWO_I / 64, H / 64, NE), 256, 0, stream>>>(w_gu, wgu_t, H, TWO_I, 1);
    transpose_cvt<<<dim3(H / 64, IDIM / 64, NE), 256, 0, stream>>>(w_dn, wdn_t, IDIM, H, 0);
    transpose_cvt<<<dim3(TWO_I / 64, H / 64, 1), 256, 0, stream>>>(w_sgu, wsgu_t, H, TWO_I, 1);
    transpose_cvt<<<dim3(H / 64, IDIM / 64, 1), 256, 0, stream>>>(w_sdn, wsdn_t, IDIM, H, 0);

    // x -> bf16 (unscaled + gathered*scaled bucket copies)
    xprep_kernel<<<dim3(NTOK, NE + 1), 256, 0, stream>>>(x, cnt, offs, bidx, bw, xs);

    // shared expert
    gateup_mfma<false><<<dim3(TWO_I / 256, NTOK / 256), 512, 0, stream>>>(xs, wsgu_t, cnt, offs, act);
    down_mfma<false><<<dim3(H / 256, NTOK / 256), 512, 0, stream>>>(act, wsdn_t, cnt, offs, bidx, gate, out);

    // routed experts
    gateup_mfma<true><<<dim3(TWO_I / 256, NTOK / 256, NE), 512, 0, stream>>>(xs, wgu_t, cnt, offs, act);
    down_mfma<true><<<dim3(H / 256, NTOK / 256, NE), 512, 0, stream>>>(act, wdn_t, cnt, offs, bidx, gate, out);
}